// Round 10
// baseline (707.621 us; speedup 1.0000x reference)
//
#include <hip/hip_runtime.h>
#include <hip/hip_bf16.h>

#define Nn 100000
#define Ee 1000000
#define INF_ 100
#define Hh 4
#define Dd 32
#define HD 128
#define Cc 47
#define HC 188
#define HCS 256
#define EPSV 1e-5f
#define SLOPE 0.2f

typedef __hip_bfloat16 bf16;
typedef __attribute__((ext_vector_type(8))) short short8;
typedef __attribute__((ext_vector_type(4))) float f32x4;

__device__ __forceinline__ float tof(bf16 v) { return __bfloat162float(v); }
__device__ __forceinline__ float b2f(unsigned short u) {
    return __uint_as_float((unsigned)u << 16);
}
__device__ __forceinline__ float ldb(const bf16* p) {
    return b2f(*(const unsigned short*)p);
}
__device__ __forceinline__ unsigned short f2u(float v) {
    bf16 t = __float2bfloat16(v);
    return *(unsigned short*)&t;
}

// ---------------- dtype detect: 1 = bf16 buffers, 0 = fp32 buffers ----------------
__global__ void detect_dtype(const unsigned* __restrict__ x, int* __restrict__ flag) {
    if (blockIdx.x == 0 && threadIdx.x == 0) {
        int good = 0;
        for (int i = 0; i < 256; ++i) {
            unsigned lo = x[i] & 0xFFFFu;
            float v = __uint_as_float(lo << 16);
            float a = fabsf(v);
            if (a > 1e-4f && a < 10.f) good++;
        }
        *flag = (good >= 128) ? 1 : 0;
    }
}

__device__ __forceinline__ float ld_any(const void* p, int i, int isbf) {
    return isbf ? tof(((const bf16*)p)[i]) : ((const float*)p)[i];
}

// ---------------- x -> canonical bf16, padded to row stride 128 ----------------
__global__ void cvt_x(const void* __restrict__ in, bf16* __restrict__ out,
                      const int* __restrict__ flag) {
    int i = blockIdx.x * blockDim.x + threadIdx.x;
    if (i >= Nn * 128) return;
    int row = i >> 7, col = i & 127;
    float v = (col < INF_) ? ld_any(in, row * INF_ + col, *flag) : 0.f;
    out[i] = __float2bfloat16(v);
}

// ---------------- small params (biases/attn/bn) -> canonical bf16 ----------------
#define NSP 15
struct CvtTab { const void* src[NSP]; int off[NSP + 1]; };

__global__ void cvt_params(CvtTab t, bf16* __restrict__ out, int total,
                           const int* __restrict__ flag) {
    int i = blockIdx.x * blockDim.x + threadIdx.x;
    if (i >= total) return;
    int isbf = *flag;
    int seg = 0;
    while (i >= t.off[seg + 1]) seg++;
    out[i] = __float2bfloat16(ld_any(t.src[seg], i - t.off[seg], isbf));
}

// ---------------- attn2 [4][47] -> packed [256]: slot 64h+4j+t = attn2[h][3j+t] ----
__global__ void pack_attn(const bf16* __restrict__ a2, bf16* __restrict__ out) {
    int i = threadIdx.x;  // 256
    int h = i >> 6, r = i & 63, j = r >> 2, t = r & 3;
    int cc = 3 * j + t;
    float v = (t < 3 && cc < Cc) ? tof(a2[h * Cc + cc]) : 0.f;
    out[i] = __float2bfloat16(v);
}

// ---------------- all 8 weight mats -> packed transposed Wt[1280][128] ----------------
#define WROWS 1280
struct PrepTab { const void* src[8]; int row0[8]; int K[8]; int M[8]; int MP[8]; };

__global__ void prep_all(PrepTab t, bf16* __restrict__ wtb, const int* __restrict__ flag) {
    int i = blockIdx.x * blockDim.x + threadIdx.x;
    if (i >= WROWS * 128) return;
    int row = i >> 7, k = i & 127;
    int isbf = *flag;
    float v = 0.f;
#pragma unroll
    for (int q = 0; q < 8; ++q) {
        if (row >= t.row0[q] && row < t.row0[q] + t.MP[q]) {
            int m = row - t.row0[q];
            if (m < t.M[q] && k < t.K[q])
                v = ld_any(t.src[q], k * t.M[q] + m, isbf);
        }
    }
    wtb[i] = __float2bfloat16(v);
}

__global__ void zero_u32(unsigned* __restrict__ p, int n) {
    int i = blockIdx.x * blockDim.x + threadIdx.x;
    if (i < n) p[i] = 0u;
}

// ---------------- CSR build: ptr[n] = lower_bound(dst, n); dst is sorted ----------------
__global__ void build_ptr(const int* __restrict__ dst, int* __restrict__ ptr) {
    int n = blockIdx.x * blockDim.x + threadIdx.x;
    if (n > Nn) return;
    if (n == Nn) { ptr[Nn] = Ee; return; }
    int lo = 0, hi = Ee;
    while (lo < hi) {
        int mid = (lo + hi) >> 1;
        if (dst[mid] < n) lo = mid + 1; else hi = mid;
    }
    ptr[n] = lo;
}

// ---------------- big-tile MFMA GEMM: 64 rows x (64*CS) cols per block -------------
// A [Nn][128] bf16 staged once in LDS, reused over CS col-subtiles per wave.
// Wt packed [*][128]; col -> (oi, lc) via constant MP. ABN: BN+relu on A staging.
// PAD47: store col lc at slot 64*(lc/47) + 4*((lc%47)/3) + (lc%47)%3, stride OSTR.
template <int MP, int NOUT, int CS, bool ABN, bool PAD47, int OSTR>
__global__ __launch_bounds__(256, 4) void gemm_big(
    const bf16* __restrict__ A, const bf16* __restrict__ Wt,
    const bf16* __restrict__ b0, const bf16* __restrict__ b1,
    const bf16* __restrict__ b2,
    bf16* __restrict__ o0, bf16* __restrict__ o1, bf16* __restrict__ o2,
    int MR, const float* __restrict__ bnp) {
    __shared__ __align__(16) bf16 Al[64 * 136];
    const int row0 = blockIdx.x * 64;
    const int tid = threadIdx.x;
#pragma unroll
    for (int j = 0; j < 4; ++j) {
        int idx = tid + j * 256;          // 0..1023 int4 slots
        int r = idx >> 4, kk = (idx & 15) * 8;
        int4 val = {0, 0, 0, 0};
        if (row0 + r < Nn) {
            val = *(const int4*)&A[(size_t)(row0 + r) * 128 + kk];
            if (ABN) {
                short8 av = *(short8*)&val;
                bf16 tmp[8];
#pragma unroll
                for (int u = 0; u < 8; ++u) {
                    float v = b2f((unsigned short)av[u]);
                    v = fmaxf(fmaf(v, bnp[kk + u], bnp[128 + kk + u]), 0.f);
                    tmp[u] = __float2bfloat16(v);
                }
                val = *(int4*)tmp;
            }
        }
        *(int4*)&Al[r * 136 + kk] = val;
    }
    __syncthreads();
    const int wave = tid >> 6, lane = tid & 63;
    const int n16 = lane & 15, quad = lane >> 4;
    const int colbase = blockIdx.y * (64 * CS) + wave * (16 * CS);
    f32x4 acc[4][CS];
#pragma unroll
    for (int rt = 0; rt < 4; ++rt)
#pragma unroll
        for (int c = 0; c < CS; ++c) acc[rt][c] = (f32x4){0.f, 0.f, 0.f, 0.f};
    const bf16* wb[CS];
#pragma unroll
    for (int c = 0; c < CS; ++c)
        wb[c] = Wt + (size_t)(colbase + c * 16 + n16) * 128 + quad * 8;
    const bf16* ap = Al + n16 * 136 + quad * 8;
#pragma unroll
    for (int ks = 0; ks < 4; ++ks) {
        short8 bf[CS];
#pragma unroll
        for (int c = 0; c < CS; ++c) bf[c] = *(const short8*)(wb[c] + ks * 32);
#pragma unroll
        for (int rt = 0; rt < 4; ++rt) {
            short8 af = *(const short8*)(ap + rt * 16 * 136 + ks * 32);
#pragma unroll
            for (int c = 0; c < CS; ++c)
                acc[rt][c] = __builtin_amdgcn_mfma_f32_16x16x32_bf16(af, bf[c], acc[rt][c], 0, 0, 0);
        }
    }
#pragma unroll
    for (int c = 0; c < CS; ++c) {
        int col = colbase + c * 16 + n16;
        int oi = col / MP, lc = col - oi * MP;
        if (oi >= NOUT || lc >= MR) continue;
        const bf16* bp = (oi == 0) ? b0 : (oi == 1) ? b1 : b2;
        bf16* o = (oi == 0) ? o0 : (oi == 1) ? o1 : o2;
        float bb = tof(bp[lc]);
        int st = lc;
        if (PAD47) {
            int head = lc / 47, cc = lc - head * 47;
            st = head * 64 + (cc / 3) * 4 + (cc - (cc / 3) * 3);
        }
#pragma unroll
        for (int rt = 0; rt < 4; ++rt) {
#pragma unroll
            for (int i = 0; i < 4; ++i) {
                int row = row0 + rt * 16 + quad * 4 + i;
                if (row < Nn)
                    o[(size_t)row * OSTR + st] = __float2bfloat16(acc[rt][c][i] + bb);
            }
        }
    }
}

// ---------------- fused GATv2 edge kernel, M=128 (layers 0,1) ----------------
// One wave per dst; lane holds cols (2*lane, 2*lane+1), head = lane>>4.
// MAX-FREE softmax. 4-edge unroll. Epilogue: +residual (RESBN: BN+relu on resb),
// conv relu, bf16 store.
template <bool RESBN>
__global__ __launch_bounds__(256) void gat_fused_128(
    const bf16* __restrict__ fs, const bf16* __restrict__ fd,
    const int* __restrict__ srcI, const int* __restrict__ ptr,
    const bf16* __restrict__ attn, const bf16* __restrict__ resb,
    const float* __restrict__ bnp, bf16* __restrict__ hout) {
    const int wave = threadIdx.x >> 6, lane = threadIdx.x & 63;
    const int d = blockIdx.x * 4 + wave;
    if (d >= Nn) return;
    const int c0 = lane * 2;
    ushort2 aq = *(const ushort2*)&attn[c0];
    float a0 = b2f(aq.x), a1 = b2f(aq.y);
    ushort2 dq = *(const ushort2*)&fd[(size_t)d * HD + c0];
    float fd0 = b2f(dq.x), fd1 = b2f(dq.y);
    float l = 0.f, O0 = 0.f, O1 = 0.f;
    int e = ptr[d];
    const int e1 = ptr[d + 1];
    for (; e + 3 < e1; e += 4) {
        int sA = srcI[e], sB = srcI[e + 1], sC = srcI[e + 2], sD = srcI[e + 3];
        ushort2 qA = *(const ushort2*)&fs[(size_t)sA * HD + c0];
        ushort2 qB = *(const ushort2*)&fs[(size_t)sB * HD + c0];
        ushort2 qC = *(const ushort2*)&fs[(size_t)sC * HD + c0];
        ushort2 qD = *(const ushort2*)&fs[(size_t)sD * HD + c0];
        float fA0 = b2f(qA.x), fA1 = b2f(qA.y);
        float fB0 = b2f(qB.x), fB1 = b2f(qB.y);
        float fC0 = b2f(qC.x), fC1 = b2f(qC.y);
        float fD0 = b2f(qD.x), fD1 = b2f(qD.y);
        float tA0 = fA0 + fd0; tA0 = fmaxf(tA0, tA0 * SLOPE);
        float tA1 = fA1 + fd1; tA1 = fmaxf(tA1, tA1 * SLOPE);
        float tB0 = fB0 + fd0; tB0 = fmaxf(tB0, tB0 * SLOPE);
        float tB1 = fB1 + fd1; tB1 = fmaxf(tB1, tB1 * SLOPE);
        float tC0 = fC0 + fd0; tC0 = fmaxf(tC0, tC0 * SLOPE);
        float tC1 = fC1 + fd1; tC1 = fmaxf(tC1, tC1 * SLOPE);
        float tD0 = fD0 + fd0; tD0 = fmaxf(tD0, tD0 * SLOPE);
        float tD1 = fD1 + fd1; tD1 = fmaxf(tD1, tD1 * SLOPE);
        float pA = fmaf(tA0, a0, tA1 * a1);
        float pB = fmaf(tB0, a0, tB1 * a1);
        float pC = fmaf(tC0, a0, tC1 * a1);
        float pD = fmaf(tD0, a0, tD1 * a1);
        pA += __shfl_xor(pA, 1); pB += __shfl_xor(pB, 1);
        pC += __shfl_xor(pC, 1); pD += __shfl_xor(pD, 1);
        pA += __shfl_xor(pA, 2); pB += __shfl_xor(pB, 2);
        pC += __shfl_xor(pC, 2); pD += __shfl_xor(pD, 2);
        pA += __shfl_xor(pA, 4); pB += __shfl_xor(pB, 4);
        pC += __shfl_xor(pC, 4); pD += __shfl_xor(pD, 4);
        pA += __shfl_xor(pA, 8); pB += __shfl_xor(pB, 8);
        pC += __shfl_xor(pC, 8); pD += __shfl_xor(pD, 8);
        float eA = __expf(pA), eB = __expf(pB), eC = __expf(pC), eD = __expf(pD);
        l += (eA + eB) + (eC + eD);
        O0 = fmaf(eA, fA0, O0); O0 = fmaf(eB, fB0, O0);
        O0 = fmaf(eC, fC0, O0); O0 = fmaf(eD, fD0, O0);
        O1 = fmaf(eA, fA1, O1); O1 = fmaf(eB, fB1, O1);
        O1 = fmaf(eC, fC1, O1); O1 = fmaf(eD, fD1, O1);
    }
    for (; e < e1; ++e) {
        int s = srcI[e];
        ushort2 fq = *(const ushort2*)&fs[(size_t)s * HD + c0];
        float f0 = b2f(fq.x), f1 = b2f(fq.y);
        float t0 = f0 + fd0; t0 = fmaxf(t0, t0 * SLOPE);
        float t1 = f1 + fd1; t1 = fmaxf(t1, t1 * SLOPE);
        float p = fmaf(t0, a0, t1 * a1);
        p += __shfl_xor(p, 1); p += __shfl_xor(p, 2);
        p += __shfl_xor(p, 4); p += __shfl_xor(p, 8);
        float pe = __expf(p);
        l += pe;
        O0 = fmaf(pe, f0, O0);
        O1 = fmaf(pe, f1, O1);
    }
    float inv = l > 0.f ? 1.f / l : 0.f;
    ushort2 rq = *(const ushort2*)&resb[(size_t)d * HD + c0];
    float r0 = b2f(rq.x), r1 = b2f(rq.y);
    if (RESBN) {
        r0 = fmaxf(fmaf(r0, bnp[c0], bnp[HD + c0]), 0.f);
        r1 = fmaxf(fmaf(r1, bnp[c0 + 1], bnp[HD + c0 + 1]), 0.f);
    }
    float v0 = fmaxf(fmaf(O0, inv, r0), 0.f);  // conv activation relu
    float v1 = fmaxf(fmaf(O1, inv, r1), 0.f);
    ushort2 ov; ov.x = f2u(v0); ov.y = f2u(v1);
    *(ushort2*)&hout[(size_t)d * HD + c0] = ov;
}

// ---------------- fused GATv2 edge kernel, layer 2, PACKED stride 256 -----------
// Lane owns slot 4*lane = 64h+4j (h=lane>>4, j=lane&15): classes 3j,3j+1,3j+2 of
// head h (t=3 and class>=47 are pads, masked by attn2p=0 / has2 guard).
// ONE ushort4 load per edge row (byte s*512 + lane*8, wave-coalesced 512B).
// MAX-FREE softmax; epilogue: +res, head-mean, log_softmax, store.
__global__ __launch_bounds__(256) void gat_fused_188(
    const bf16* __restrict__ fs, const bf16* __restrict__ fd,
    const int* __restrict__ srcI, const int* __restrict__ ptr,
    const bf16* __restrict__ attnP, const bf16* __restrict__ rs,
    void* __restrict__ out, const int* __restrict__ flag) {
    const int wave = threadIdx.x >> 6, lane = threadIdx.x & 63;
    const int d = blockIdx.x * 4 + wave;
    if (d >= Nn) return;
    const int h = lane >> 4, j = lane & 15;
    const int sl = lane * 4;
    const bool has2 = (j < 15);
    ushort4 aq = *(const ushort4*)&attnP[sl];
    float a0 = b2f(aq.x), a1 = b2f(aq.y), a2 = b2f(aq.z);  // pads are 0
    ushort4 dq = *(const ushort4*)&fd[(size_t)d * HCS + sl];
    float fd0 = b2f(dq.x), fd1 = b2f(dq.y), fd2 = b2f(dq.z);
    float l = 0.f, O0 = 0.f, O1 = 0.f, O2 = 0.f;
    int e = ptr[d];
    const int e1 = ptr[d + 1];
    for (; e + 1 < e1; e += 2) {
        int sa = srcI[e], sb = srcI[e + 1];
        ushort4 qa = *(const ushort4*)&fs[(size_t)sa * HCS + sl];
        ushort4 qb = *(const ushort4*)&fs[(size_t)sb * HCS + sl];
        float fa0 = b2f(qa.x), fa1 = b2f(qa.y), fa2 = b2f(qa.z);
        float fb0 = b2f(qb.x), fb1 = b2f(qb.y), fb2 = b2f(qb.z);
        float ta0 = fa0 + fd0; ta0 = fmaxf(ta0, ta0 * SLOPE);
        float ta1 = fa1 + fd1; ta1 = fmaxf(ta1, ta1 * SLOPE);
        float ta2 = fa2 + fd2; ta2 = fmaxf(ta2, ta2 * SLOPE);
        float tb0 = fb0 + fd0; tb0 = fmaxf(tb0, tb0 * SLOPE);
        float tb1 = fb1 + fd1; tb1 = fmaxf(tb1, tb1 * SLOPE);
        float tb2 = fb2 + fd2; tb2 = fmaxf(tb2, tb2 * SLOPE);
        float pa = fmaf(ta0, a0, fmaf(ta1, a1, ta2 * a2));
        float pb = fmaf(tb0, a0, fmaf(tb1, a1, tb2 * a2));
        pa += __shfl_xor(pa, 1); pb += __shfl_xor(pb, 1);
        pa += __shfl_xor(pa, 2); pb += __shfl_xor(pb, 2);
        pa += __shfl_xor(pa, 4); pb += __shfl_xor(pb, 4);
        pa += __shfl_xor(pa, 8); pb += __shfl_xor(pb, 8);
        float ea = __expf(pa), eb = __expf(pb);
        l += ea + eb;
        O0 = fmaf(ea, fa0, O0); O0 = fmaf(eb, fb0, O0);
        O1 = fmaf(ea, fa1, O1); O1 = fmaf(eb, fb1, O1);
        O2 = fmaf(ea, fa2, O2); O2 = fmaf(eb, fb2, O2);
    }
    if (e < e1) {
        int s = srcI[e];
        ushort4 fq = *(const ushort4*)&fs[(size_t)s * HCS + sl];
        float f0 = b2f(fq.x), f1 = b2f(fq.y), f2 = b2f(fq.z);
        float t0 = f0 + fd0; t0 = fmaxf(t0, t0 * SLOPE);
        float t1 = f1 + fd1; t1 = fmaxf(t1, t1 * SLOPE);
        float t2 = f2 + fd2; t2 = fmaxf(t2, t2 * SLOPE);
        float p = fmaf(t0, a0, fmaf(t1, a1, t2 * a2));
        p += __shfl_xor(p, 1); p += __shfl_xor(p, 2);
        p += __shfl_xor(p, 4); p += __shfl_xor(p, 8);
        float pe = __expf(p);
        l += pe;
        O0 = fmaf(pe, f0, O0);
        O1 = fmaf(pe, f1, O1);
        O2 = fmaf(pe, f2, O2);
    }
    // epilogue: +res, head-mean across lane groups, log_softmax, store
    float inv = l > 0.f ? 1.f / l : 0.f;
    ushort4 rq = *(const ushort4*)&rs[(size_t)d * HCS + sl];
    float v0 = fmaf(O0, inv, b2f(rq.x));
    float v1 = fmaf(O1, inv, b2f(rq.y));
    float v2 = has2 ? fmaf(O2, inv, b2f(rq.z)) : 0.f;
    v0 += __shfl_xor(v0, 16); v0 += __shfl_xor(v0, 32); v0 *= 0.25f;
    v1 += __shfl_xor(v1, 16); v1 += __shfl_xor(v1, 32); v1 *= 0.25f;
    v2 += __shfl_xor(v2, 16); v2 += __shfl_xor(v2, 32); v2 *= 0.25f;
    float mx = fmaxf(v0, v1);
    if (has2) mx = fmaxf(mx, v2);
    mx = fmaxf(mx, __shfl_xor(mx, 1)); mx = fmaxf(mx, __shfl_xor(mx, 2));
    mx = fmaxf(mx, __shfl_xor(mx, 4)); mx = fmaxf(mx, __shfl_xor(mx, 8));
    float sm = __expf(v0 - mx) + __expf(v1 - mx) + (has2 ? __expf(v2 - mx) : 0.f);
    sm += __shfl_xor(sm, 1); sm += __shfl_xor(sm, 2);
    sm += __shfl_xor(sm, 4); sm += __shfl_xor(sm, 8);
    if (h == 0) {
        float ls = mx + logf(sm);
        int c = 3 * j;
        if (*flag) {
            bf16* o = (bf16*)out + (size_t)d * Cc;
            o[c] = __float2bfloat16(v0 - ls);
            o[c + 1] = __float2bfloat16(v1 - ls);
            if (has2) o[c + 2] = __float2bfloat16(v2 - ls);
        } else {
            float* o = (float*)out + (size_t)d * Cc;
            o[c] = v0 - ls;
            o[c + 1] = v1 - ls;
            if (has2) o[c + 2] = v2 - ls;
        }
    }
}

// ---------------- per-column BN stats over bf16 h (atomic combine) ----------------
__global__ void col_stats(const bf16* __restrict__ in, float* __restrict__ sums) {
    int c = threadIdx.x;  // 128
    int r0 = blockIdx.x * 256;
    int r1 = r0 + 256; if (r1 > Nn) r1 = Nn;
    float s = 0.f, s2 = 0.f;
    for (int r = r0; r < r1; ++r) {
        float v = ldb(&in[(size_t)r * HD + c]);
        s += v; s2 += v * v;
    }
    atomicAdd(&sums[c], s);
    atomicAdd(&sums[HD + c], s2);
}

__global__ void bn_finalize(const float* __restrict__ sums, const bf16* __restrict__ g,
                            const bf16* __restrict__ be, float* __restrict__ ss) {
    int c = threadIdx.x;  // 128
    float mu = sums[c] * (1.f / Nn);
    float var = sums[HD + c] * (1.f / Nn) - mu * mu;
    float sc = tof(g[c]) * rsqrtf(var + EPSV);
    ss[c] = sc;
    ss[HD + c] = tof(be[c]) - mu * sc;
}

extern "C" void kernel_launch(void* const* d_in, const int* in_sizes, int n_in,
                              void* d_out, int out_size, void* d_ws, size_t ws_size,
                              hipStream_t stream) {
    (void)in_sizes; (void)n_in; (void)out_size; (void)ws_size;
    const void* x = d_in[0];
    const int* src = (const int*)d_in[1];
    const int* dst = (const int*)d_in[2];

    char* ws = (char*)d_ws;
    size_t off = 0;
    auto alloc = [&](size_t bytes) {
        void* p = ws + off;
        off += (bytes + 255) & ~(size_t)255;
        return p;
    };
    // Aliases: hbB = rb (rb dead after L0 gat, hbB written in L1 gat);
    //          rs [Nn][HCS] = xb+hbA (both dead before L2 GEMM writes rs).
    bf16* xb = (bf16*)alloc((size_t)Nn * 128 * 2);    // 25.6 MB
    bf16* hbA = (bf16*)alloc((size_t)Nn * HD * 2);    // 25.6 MB
    bf16* rb = (bf16*)alloc((size_t)Nn * HD * 2);     // 25.6 MB
    bf16* hbB = rb;
    bf16* rs = xb;                                    // spans xb+hbA = 51.2 MB exactly
    bf16* fs = (bf16*)alloc((size_t)Nn * HCS * 2);    // 51.2 MB
    bf16* fd = (bf16*)alloc((size_t)Nn * HCS * 2);    // 51.2 MB
    int* ptr = (int*)alloc((Nn + 1) * 4);             // 400 KB
    bf16* wtb = (bf16*)alloc((size_t)WROWS * 128 * 2);// 328 KB
    float* bns = (float*)alloc(2 * HD * 4);
    float* bnss0 = (float*)alloc(2 * HD * 4);
    float* bnss1 = (float*)alloc(2 * HD * 4);
    bf16* pb = (bf16*)alloc(4096 * 2);
    bf16* attn2p = (bf16*)alloc(256 * 2);
    int* flag = (int*)alloc(256);

    // ---- small-param conversion (biases/attn/bn): d_in idx -> pb arena ----
    static const int spIdx[NSP] = {4, 6, 7, 9, 11, 13, 14, 16, 18, 19, 21, 22, 23, 24, 25};
    static const int spSz[NSP]  = {HD, HD, HD, HD, HD, HD, HD, HC, HC, HC, HC, HD, HD, HD, HD};
    CvtTab tab;
    int tot = 0;
    for (int i = 0; i < NSP; ++i) { tab.src[i] = d_in[spIdx[i]]; tab.off[i] = tot; tot += spSz[i]; }
    tab.off[NSP] = tot;
    const bf16 *bsrc0 = pb + tab.off[0], *bdst0 = pb + tab.off[1], *attn0 = pb + tab.off[2],
               *bres0 = pb + tab.off[3], *bsrc1 = pb + tab.off[4], *bdst1 = pb + tab.off[5],
               *attn1 = pb + tab.off[6], *bsrc2 = pb + tab.off[7], *bdst2 = pb + tab.off[8],
               *attn2 = pb + tab.off[9], *bres2 = pb + tab.off[10],
               *g0 = pb + tab.off[11], *be0 = pb + tab.off[12],
               *g1 = pb + tab.off[13], *be1 = pb + tab.off[14];

    // ---- packed Wt: rows [0,384)=L0, [384,640)=L1, [640,1216)=L2 @MP=192, pad->1280 ----
    PrepTab pt;
    static const int wIdx[8] = {3, 5, 8, 10, 12, 15, 17, 20};
    static const int wK[8]   = {INF_, INF_, INF_, HD, HD, HD, HD, HD};
    static const int wM[8]   = {HD, HD, HD, HD, HD, HC, HC, HC};
    static const int wMP[8]  = {128, 128, 128, 128, 128, 192, 192, 192};
    static const int wR0[8]  = {0, 128, 256, 384, 512, 640, 832, 1024};
    for (int i = 0; i < 8; ++i) {
        pt.src[i] = d_in[wIdx[i]]; pt.row0[i] = wR0[i];
        pt.K[i] = wK[i]; pt.M[i] = wM[i]; pt.MP[i] = wMP[i];
    }

    detect_dtype<<<1, 64, 0, stream>>>((const unsigned*)x, flag);
    cvt_x<<<(Nn * 128 + 255) / 256, 256, 0, stream>>>(x, xb, flag);
    cvt_params<<<(tot + 255) / 256, 256, 0, stream>>>(tab, pb, tot, flag);
    pack_attn<<<1, 256, 0, stream>>>(attn2, attn2p);
    prep_all<<<(WROWS * 128 + 255) / 256, 256, 0, stream>>>(pt, wtb, flag);
    build_ptr<<<(Nn + 256) / 256, 256, 0, stream>>>(dst, ptr);

    const int fusedGrid = (Nn + 3) / 4;
    const int statsGrid = (Nn + 255) / 256;
    const int rowBlk = (Nn + 63) / 64;  // 1563

    // ---------------- layer 0 (384 cols: y=2 x CS=3, A fetched 2x) ----------------
    gemm_big<128, 3, 3, false, false, HD><<<dim3(rowBlk, 2), 256, 0, stream>>>(
        xb, wtb, bsrc0, bdst0, bres0, fs, fd, rb, HD, nullptr);
    gat_fused_128<false><<<fusedGrid, 256, 0, stream>>>(fs, fd, src, ptr, attn0,
                                                        rb, nullptr, hbA);
    zero_u32<<<1, 256, 0, stream>>>((unsigned*)bns, 2 * HD);
    col_stats<<<statsGrid, 128, 0, stream>>>(hbA, bns);
    bn_finalize<<<1, HD, 0, stream>>>(bns, g0, be0, bnss0);

    // ---------------- layer 1 ----------------
    gemm_big<128, 2, 2, true, false, HD><<<dim3(rowBlk, 2), 256, 0, stream>>>(
        hbA, wtb + (size_t)384 * 128, bsrc1, bdst1, nullptr, fs, fd, nullptr, HD, bnss0);
    gat_fused_128<true><<<fusedGrid, 256, 0, stream>>>(fs, fd, src, ptr, attn1,
                                                       hbA, bnss0, hbB);
    zero_u32<<<1, 256, 0, stream>>>((unsigned*)bns, 2 * HD);
    col_stats<<<statsGrid, 128, 0, stream>>>(hbB, bns);
    bn_finalize<<<1, HD, 0, stream>>>(bns, g1, be1, bnss1);

    // ---------------- layer 2 (packed 4-per-lane stride-256 outputs) ----------------
    gemm_big<192, 3, 3, true, true, HCS><<<dim3(rowBlk, 3), 256, 0, stream>>>(
        hbB, wtb + (size_t)640 * 128, bsrc2, bdst2, bres2, fs, fd, rs, HC, bnss1);
    gat_fused_188<<<fusedGrid, 256, 0, stream>>>(fs, fd, src, ptr, attn2p, rs,
                                                 d_out, flag);
}

// Round 11
// 674.263 us; speedup vs baseline: 1.0495x; 1.0495x over previous
//
#include <hip/hip_runtime.h>
#include <hip/hip_bf16.h>

#define Nn 100000
#define Ee 1000000
#define INF_ 100
#define Hh 4
#define Dd 32
#define HD 128
#define Cc 47
#define HC 188
#define HCP 192
#define EPSV 1e-5f
#define SLOPE 0.2f

typedef __hip_bfloat16 bf16;
typedef __attribute__((ext_vector_type(8))) short short8;
typedef __attribute__((ext_vector_type(4))) float f32x4;

__device__ __forceinline__ float tof(bf16 v) { return __bfloat162float(v); }
__device__ __forceinline__ float b2f(unsigned short u) {
    return __uint_as_float((unsigned)u << 16);
}
__device__ __forceinline__ float ldb(const bf16* p) {
    return b2f(*(const unsigned short*)p);
}
__device__ __forceinline__ unsigned short f2u(float v) {
    bf16 t = __float2bfloat16(v);
    return *(unsigned short*)&t;
}

// ---------------- dtype detect: 1 = bf16 buffers, 0 = fp32 buffers ----------------
__global__ void detect_dtype(const unsigned* __restrict__ x, int* __restrict__ flag) {
    if (blockIdx.x == 0 && threadIdx.x == 0) {
        int good = 0;
        for (int i = 0; i < 256; ++i) {
            unsigned lo = x[i] & 0xFFFFu;
            float v = __uint_as_float(lo << 16);
            float a = fabsf(v);
            if (a > 1e-4f && a < 10.f) good++;
        }
        *flag = (good >= 128) ? 1 : 0;
    }
}

__device__ __forceinline__ float ld_any(const void* p, int i, int isbf) {
    return isbf ? tof(((const bf16*)p)[i]) : ((const float*)p)[i];
}

// ---------------- x -> canonical bf16, padded to row stride 128 ----------------
__global__ void cvt_x(const void* __restrict__ in, bf16* __restrict__ out,
                      const int* __restrict__ flag) {
    int i = blockIdx.x * blockDim.x + threadIdx.x;
    if (i >= Nn * 128) return;
    int row = i >> 7, col = i & 127;
    float v = (col < INF_) ? ld_any(in, row * INF_ + col, *flag) : 0.f;
    out[i] = __float2bfloat16(v);
}

// ---------------- small params (biases/attn/bn) -> canonical bf16 ----------------
#define NSP 15
struct CvtTab { const void* src[NSP]; int off[NSP + 1]; };

__global__ void cvt_params(CvtTab t, bf16* __restrict__ out, int total,
                           const int* __restrict__ flag) {
    int i = blockIdx.x * blockDim.x + threadIdx.x;
    if (i >= total) return;
    int isbf = *flag;
    int seg = 0;
    while (i >= t.off[seg + 1]) seg++;
    out[i] = __float2bfloat16(ld_any(t.src[seg], i - t.off[seg], isbf));
}

// ---------------- all 8 weight mats -> packed transposed Wt[1280][128] ----------------
#define WROWS 1280
struct PrepTab { const void* src[8]; int row0[8]; int K[8]; int M[8]; int MP[8]; };

__global__ void prep_all(PrepTab t, bf16* __restrict__ wtb, const int* __restrict__ flag) {
    int i = blockIdx.x * blockDim.x + threadIdx.x;
    if (i >= WROWS * 128) return;
    int row = i >> 7, k = i & 127;
    int isbf = *flag;
    float v = 0.f;
#pragma unroll
    for (int q = 0; q < 8; ++q) {
        if (row >= t.row0[q] && row < t.row0[q] + t.MP[q]) {
            int m = row - t.row0[q];
            if (m < t.M[q] && k < t.K[q])
                v = ld_any(t.src[q], k * t.M[q] + m, isbf);
        }
    }
    wtb[i] = __float2bfloat16(v);
}

__global__ void zero_u32(unsigned* __restrict__ p, int n) {
    int i = blockIdx.x * blockDim.x + threadIdx.x;
    if (i < n) p[i] = 0u;
}

// ---------------- CSR build: ptr[n] = lower_bound(dst, n); dst is sorted ----------------
__global__ void build_ptr(const int* __restrict__ dst, int* __restrict__ ptr) {
    int n = blockIdx.x * blockDim.x + threadIdx.x;
    if (n > Nn) return;
    if (n == Nn) { ptr[Nn] = Ee; return; }
    int lo = 0, hi = Ee;
    while (lo < hi) {
        int mid = (lo + hi) >> 1;
        if (dst[mid] < n) lo = mid + 1; else hi = mid;
    }
    ptr[n] = lo;
}

// ---------------- big-tile MFMA GEMM: 64 rows x (64*CS) cols per block -------------
// A [Nn][128] bf16 staged once in LDS, reused over CS col-subtiles per wave.
// Wt packed [*][128]; col -> (oi, lc) via constant MP. ABN: BN+relu on A staging.
// PAD47: store col lc remapped to lc + lc/47 (head-major 48-pad), stride OSTR.
template <int MP, int NOUT, int CS, bool ABN, bool PAD47, int OSTR>
__global__ __launch_bounds__(256, 4) void gemm_big(
    const bf16* __restrict__ A, const bf16* __restrict__ Wt,
    const bf16* __restrict__ b0, const bf16* __restrict__ b1,
    const bf16* __restrict__ b2,
    bf16* __restrict__ o0, bf16* __restrict__ o1, bf16* __restrict__ o2,
    int MR, const float* __restrict__ bnp) {
    __shared__ __align__(16) bf16 Al[64 * 136];
    const int row0 = blockIdx.x * 64;
    const int tid = threadIdx.x;
#pragma unroll
    for (int j = 0; j < 4; ++j) {
        int idx = tid + j * 256;          // 0..1023 int4 slots
        int r = idx >> 4, kk = (idx & 15) * 8;
        int4 val = {0, 0, 0, 0};
        if (row0 + r < Nn) {
            val = *(const int4*)&A[(size_t)(row0 + r) * 128 + kk];
            if (ABN) {
                short8 av = *(short8*)&val;
                bf16 tmp[8];
#pragma unroll
                for (int u = 0; u < 8; ++u) {
                    float v = b2f((unsigned short)av[u]);
                    v = fmaxf(fmaf(v, bnp[kk + u], bnp[128 + kk + u]), 0.f);
                    tmp[u] = __float2bfloat16(v);
                }
                val = *(int4*)tmp;
            }
        }
        *(int4*)&Al[r * 136 + kk] = val;
    }
    __syncthreads();
    const int wave = tid >> 6, lane = tid & 63;
    const int n16 = lane & 15, quad = lane >> 4;
    const int colbase = blockIdx.y * (64 * CS) + wave * (16 * CS);
    f32x4 acc[4][CS];
#pragma unroll
    for (int rt = 0; rt < 4; ++rt)
#pragma unroll
        for (int c = 0; c < CS; ++c) acc[rt][c] = (f32x4){0.f, 0.f, 0.f, 0.f};
    const bf16* wb[CS];
#pragma unroll
    for (int c = 0; c < CS; ++c)
        wb[c] = Wt + (size_t)(colbase + c * 16 + n16) * 128 + quad * 8;
    const bf16* ap = Al + n16 * 136 + quad * 8;
#pragma unroll
    for (int ks = 0; ks < 4; ++ks) {
        short8 bf[CS];
#pragma unroll
        for (int c = 0; c < CS; ++c) bf[c] = *(const short8*)(wb[c] + ks * 32);
#pragma unroll
        for (int rt = 0; rt < 4; ++rt) {
            short8 af = *(const short8*)(ap + rt * 16 * 136 + ks * 32);
#pragma unroll
            for (int c = 0; c < CS; ++c)
                acc[rt][c] = __builtin_amdgcn_mfma_f32_16x16x32_bf16(af, bf[c], acc[rt][c], 0, 0, 0);
        }
    }
#pragma unroll
    for (int c = 0; c < CS; ++c) {
        int col = colbase + c * 16 + n16;
        int oi = col / MP, lc = col - oi * MP;
        if (oi >= NOUT || lc >= MR) continue;
        const bf16* bp = (oi == 0) ? b0 : (oi == 1) ? b1 : b2;
        bf16* o = (oi == 0) ? o0 : (oi == 1) ? o1 : o2;
        float bb = tof(bp[lc]);
        int st = PAD47 ? (lc + lc / 47) : lc;
#pragma unroll
        for (int rt = 0; rt < 4; ++rt) {
#pragma unroll
            for (int i = 0; i < 4; ++i) {
                int row = row0 + rt * 16 + quad * 4 + i;
                if (row < Nn)
                    o[(size_t)row * OSTR + st] = __float2bfloat16(acc[rt][c][i] + bb);
            }
        }
    }
}

// ---------------- fused GATv2 edge kernel, M=128 (layers 0,1) ----------------
// One wave per dst; lane holds cols (2*lane, 2*lane+1), head = lane>>4.
// MAX-FREE softmax. lrelu fold: lrelu(x)*a = x*(0.6a) + |x|*(0.4a).
// 4-edge unroll. Epilogue: +residual (RESBN: BN+relu on resb), conv relu, store.
template <bool RESBN>
__global__ __launch_bounds__(256) void gat_fused_128(
    const bf16* __restrict__ fs, const bf16* __restrict__ fd,
    const int* __restrict__ srcI, const int* __restrict__ ptr,
    const bf16* __restrict__ attn, const bf16* __restrict__ resb,
    const float* __restrict__ bnp, bf16* __restrict__ hout) {
    const int wave = threadIdx.x >> 6, lane = threadIdx.x & 63;
    const int d = blockIdx.x * 4 + wave;
    if (d >= Nn) return;
    const int c0 = lane * 2;
    ushort2 aq = *(const ushort2*)&attn[c0];
    float A0 = 0.6f * b2f(aq.x), B0 = 0.4f * b2f(aq.x);
    float A1 = 0.6f * b2f(aq.y), B1 = 0.4f * b2f(aq.y);
    ushort2 dq = *(const ushort2*)&fd[(size_t)d * HD + c0];
    float fd0 = b2f(dq.x), fd1 = b2f(dq.y);
    float l = 0.f, O0 = 0.f, O1 = 0.f;
    int e = ptr[d];
    const int e1 = ptr[d + 1];
    for (; e + 3 < e1; e += 4) {
        int sA = srcI[e], sB = srcI[e + 1], sC = srcI[e + 2], sD = srcI[e + 3];
        ushort2 qA = *(const ushort2*)&fs[(size_t)sA * HD + c0];
        ushort2 qB = *(const ushort2*)&fs[(size_t)sB * HD + c0];
        ushort2 qC = *(const ushort2*)&fs[(size_t)sC * HD + c0];
        ushort2 qD = *(const ushort2*)&fs[(size_t)sD * HD + c0];
        float fA0 = b2f(qA.x), fA1 = b2f(qA.y);
        float fB0 = b2f(qB.x), fB1 = b2f(qB.y);
        float fC0 = b2f(qC.x), fC1 = b2f(qC.y);
        float fD0 = b2f(qD.x), fD1 = b2f(qD.y);
        float xA0 = fA0 + fd0, xA1 = fA1 + fd1;
        float xB0 = fB0 + fd0, xB1 = fB1 + fd1;
        float xC0 = fC0 + fd0, xC1 = fC1 + fd1;
        float xD0 = fD0 + fd0, xD1 = fD1 + fd1;
        float pA = fmaf(xA0, A0, fmaf(fabsf(xA0), B0, fmaf(xA1, A1, fabsf(xA1) * B1)));
        float pB = fmaf(xB0, A0, fmaf(fabsf(xB0), B0, fmaf(xB1, A1, fabsf(xB1) * B1)));
        float pC = fmaf(xC0, A0, fmaf(fabsf(xC0), B0, fmaf(xC1, A1, fabsf(xC1) * B1)));
        float pD = fmaf(xD0, A0, fmaf(fabsf(xD0), B0, fmaf(xD1, A1, fabsf(xD1) * B1)));
        pA += __shfl_xor(pA, 1); pB += __shfl_xor(pB, 1);
        pC += __shfl_xor(pC, 1); pD += __shfl_xor(pD, 1);
        pA += __shfl_xor(pA, 2); pB += __shfl_xor(pB, 2);
        pC += __shfl_xor(pC, 2); pD += __shfl_xor(pD, 2);
        pA += __shfl_xor(pA, 4); pB += __shfl_xor(pB, 4);
        pC += __shfl_xor(pC, 4); pD += __shfl_xor(pD, 4);
        pA += __shfl_xor(pA, 8); pB += __shfl_xor(pB, 8);
        pC += __shfl_xor(pC, 8); pD += __shfl_xor(pD, 8);
        float eA = __expf(pA), eB = __expf(pB), eC = __expf(pC), eD = __expf(pD);
        l += (eA + eB) + (eC + eD);
        O0 = fmaf(eA, fA0, O0); O0 = fmaf(eB, fB0, O0);
        O0 = fmaf(eC, fC0, O0); O0 = fmaf(eD, fD0, O0);
        O1 = fmaf(eA, fA1, O1); O1 = fmaf(eB, fB1, O1);
        O1 = fmaf(eC, fC1, O1); O1 = fmaf(eD, fD1, O1);
    }
    for (; e < e1; ++e) {
        int s = srcI[e];
        ushort2 fq = *(const ushort2*)&fs[(size_t)s * HD + c0];
        float f0 = b2f(fq.x), f1 = b2f(fq.y);
        float x0 = f0 + fd0, x1 = f1 + fd1;
        float p = fmaf(x0, A0, fmaf(fabsf(x0), B0, fmaf(x1, A1, fabsf(x1) * B1)));
        p += __shfl_xor(p, 1); p += __shfl_xor(p, 2);
        p += __shfl_xor(p, 4); p += __shfl_xor(p, 8);
        float pe = __expf(p);
        l += pe;
        O0 = fmaf(pe, f0, O0);
        O1 = fmaf(pe, f1, O1);
    }
    float inv = l > 0.f ? 1.f / l : 0.f;
    ushort2 rq = *(const ushort2*)&resb[(size_t)d * HD + c0];
    float r0 = b2f(rq.x), r1 = b2f(rq.y);
    if (RESBN) {
        r0 = fmaxf(fmaf(r0, bnp[c0], bnp[HD + c0]), 0.f);
        r1 = fmaxf(fmaf(r1, bnp[c0 + 1], bnp[HD + c0 + 1]), 0.f);
    }
    float v0 = fmaxf(fmaf(O0, inv, r0), 0.f);  // conv activation relu
    float v1 = fmaxf(fmaf(O1, inv, r1), 0.f);
    ushort2 ov; ov.x = f2u(v0); ov.y = f2u(v1);
    *(ushort2*)&hout[(size_t)d * HD + c0] = ov;
}

// ---------------- fused GATv2 edge kernel, layer 2, PADDED stride 192 -----------
// fs/fd/rs stored head-major 48-pad: orig col h*47+cc at h*48+cc; pad col 47
// never written (garbage) but masked by a2=0 / epilogue guard (finite).
// Lane = 16*h + j owns cc {j, j+16, j+32}; MAX-FREE softmax; lrelu fold;
// 4-edge unroll. Epilogue: +res, head-mean, log_softmax, store.
__global__ __launch_bounds__(256) void gat_fused_188(
    const bf16* __restrict__ fs, const bf16* __restrict__ fd,
    const int* __restrict__ srcI, const int* __restrict__ ptr,
    const bf16* __restrict__ attn, const bf16* __restrict__ rs,
    void* __restrict__ out, const int* __restrict__ flag) {
    const int wave = threadIdx.x >> 6, lane = threadIdx.x & 63;
    const int d = blockIdx.x * 4 + wave;
    if (d >= Nn) return;
    const int h = lane >> 4, j = lane & 15;
    const int c0 = h * 48 + j;        // padded layout
    const int ca = h * Cc + j;        // attn is unpadded [188]
    const bool has2 = (j < 15);
    float a0 = ldb(&attn[ca]);
    float a1 = ldb(&attn[ca + 16]);
    float a2 = has2 ? ldb(&attn[ca + 32]) : 0.f;
    float A0 = 0.6f * a0, B0 = 0.4f * a0;
    float A1 = 0.6f * a1, B1 = 0.4f * a1;
    float A2 = 0.6f * a2, B2 = 0.4f * a2;
    const bf16* fdr = fd + (size_t)d * HCP;
    float fd0 = ldb(&fdr[c0]);
    float fd1 = ldb(&fdr[c0 + 16]);
    float fd2 = ldb(&fdr[c0 + 32]);   // pad garbage OK: A2=B2=0 masks
    float l = 0.f, O0 = 0.f, O1 = 0.f, O2 = 0.f;
    int e = ptr[d];
    const int e1 = ptr[d + 1];
    for (; e + 3 < e1; e += 4) {
        int sA = srcI[e], sB = srcI[e + 1], sC = srcI[e + 2], sD = srcI[e + 3];
        const bf16* frA = fs + (size_t)sA * HCP;
        const bf16* frB = fs + (size_t)sB * HCP;
        const bf16* frC = fs + (size_t)sC * HCP;
        const bf16* frD = fs + (size_t)sD * HCP;
        float fA0 = ldb(&frA[c0]), fA1 = ldb(&frA[c0 + 16]), fA2 = ldb(&frA[c0 + 32]);
        float fB0 = ldb(&frB[c0]), fB1 = ldb(&frB[c0 + 16]), fB2 = ldb(&frB[c0 + 32]);
        float fC0 = ldb(&frC[c0]), fC1 = ldb(&frC[c0 + 16]), fC2 = ldb(&frC[c0 + 32]);
        float fD0 = ldb(&frD[c0]), fD1 = ldb(&frD[c0 + 16]), fD2 = ldb(&frD[c0 + 32]);
        float xA0 = fA0 + fd0, xA1 = fA1 + fd1, xA2 = fA2 + fd2;
        float xB0 = fB0 + fd0, xB1 = fB1 + fd1, xB2 = fB2 + fd2;
        float xC0 = fC0 + fd0, xC1 = fC1 + fd1, xC2 = fC2 + fd2;
        float xD0 = fD0 + fd0, xD1 = fD1 + fd1, xD2 = fD2 + fd2;
        float pA = fmaf(xA0, A0, fmaf(fabsf(xA0), B0, fmaf(xA1, A1, fmaf(fabsf(xA1), B1,
                   fmaf(xA2, A2, fabsf(xA2) * B2)))));
        float pB = fmaf(xB0, A0, fmaf(fabsf(xB0), B0, fmaf(xB1, A1, fmaf(fabsf(xB1), B1,
                   fmaf(xB2, A2, fabsf(xB2) * B2)))));
        float pC = fmaf(xC0, A0, fmaf(fabsf(xC0), B0, fmaf(xC1, A1, fmaf(fabsf(xC1), B1,
                   fmaf(xC2, A2, fabsf(xC2) * B2)))));
        float pD = fmaf(xD0, A0, fmaf(fabsf(xD0), B0, fmaf(xD1, A1, fmaf(fabsf(xD1), B1,
                   fmaf(xD2, A2, fabsf(xD2) * B2)))));
        pA += __shfl_xor(pA, 1); pB += __shfl_xor(pB, 1);
        pC += __shfl_xor(pC, 1); pD += __shfl_xor(pD, 1);
        pA += __shfl_xor(pA, 2); pB += __shfl_xor(pB, 2);
        pC += __shfl_xor(pC, 2); pD += __shfl_xor(pD, 2);
        pA += __shfl_xor(pA, 4); pB += __shfl_xor(pB, 4);
        pC += __shfl_xor(pC, 4); pD += __shfl_xor(pD, 4);
        pA += __shfl_xor(pA, 8); pB += __shfl_xor(pB, 8);
        pC += __shfl_xor(pC, 8); pD += __shfl_xor(pD, 8);
        float eA = __expf(pA), eB = __expf(pB), eC = __expf(pC), eD = __expf(pD);
        l += (eA + eB) + (eC + eD);
        O0 = fmaf(eA, fA0, O0); O0 = fmaf(eB, fB0, O0);
        O0 = fmaf(eC, fC0, O0); O0 = fmaf(eD, fD0, O0);
        O1 = fmaf(eA, fA1, O1); O1 = fmaf(eB, fB1, O1);
        O1 = fmaf(eC, fC1, O1); O1 = fmaf(eD, fD1, O1);
        O2 = fmaf(eA, fA2, O2); O2 = fmaf(eB, fB2, O2);
        O2 = fmaf(eC, fC2, O2); O2 = fmaf(eD, fD2, O2);
    }
    for (; e < e1; ++e) {
        int s = srcI[e];
        const bf16* fr = fs + (size_t)s * HCP;
        float f0 = ldb(&fr[c0]);
        float f1 = ldb(&fr[c0 + 16]);
        float f2 = ldb(&fr[c0 + 32]);
        float x0 = f0 + fd0, x1 = f1 + fd1, x2 = f2 + fd2;
        float p = fmaf(x0, A0, fmaf(fabsf(x0), B0, fmaf(x1, A1, fmaf(fabsf(x1), B1,
                  fmaf(x2, A2, fabsf(x2) * B2)))));
        p += __shfl_xor(p, 1); p += __shfl_xor(p, 2);
        p += __shfl_xor(p, 4); p += __shfl_xor(p, 8);
        float pe = __expf(p);
        l += pe;
        O0 = fmaf(pe, f0, O0);
        O1 = fmaf(pe, f1, O1);
        O2 = fmaf(pe, f2, O2);
    }
    // epilogue: +res, head-mean across lane groups, log_softmax, store
    float inv = l > 0.f ? 1.f / l : 0.f;
    const bf16* rr = rs + (size_t)d * HCP;
    float v0 = fmaf(O0, inv, ldb(&rr[c0]));
    float v1 = fmaf(O1, inv, ldb(&rr[c0 + 16]));
    float v2 = has2 ? fmaf(O2, inv, ldb(&rr[c0 + 32])) : 0.f;
    v0 += __shfl_xor(v0, 16); v0 += __shfl_xor(v0, 32); v0 *= 0.25f;
    v1 += __shfl_xor(v1, 16); v1 += __shfl_xor(v1, 32); v1 *= 0.25f;
    v2 += __shfl_xor(v2, 16); v2 += __shfl_xor(v2, 32); v2 *= 0.25f;
    float mx = fmaxf(v0, v1);
    if (has2) mx = fmaxf(mx, v2);
    mx = fmaxf(mx, __shfl_xor(mx, 1)); mx = fmaxf(mx, __shfl_xor(mx, 2));
    mx = fmaxf(mx, __shfl_xor(mx, 4)); mx = fmaxf(mx, __shfl_xor(mx, 8));
    float sm = __expf(v0 - mx) + __expf(v1 - mx) + (has2 ? __expf(v2 - mx) : 0.f);
    sm += __shfl_xor(sm, 1); sm += __shfl_xor(sm, 2);
    sm += __shfl_xor(sm, 4); sm += __shfl_xor(sm, 8);
    if (h == 0) {
        float ls = mx + logf(sm);
        if (*flag) {
            bf16* o = (bf16*)out + (size_t)d * Cc;
            o[j] = __float2bfloat16(v0 - ls);
            o[j + 16] = __float2bfloat16(v1 - ls);
            if (has2) o[j + 32] = __float2bfloat16(v2 - ls);
        } else {
            float* o = (float*)out + (size_t)d * Cc;
            o[j] = v0 - ls;
            o[j + 16] = v1 - ls;
            if (has2) o[j + 32] = v2 - ls;
        }
    }
}

// ---------------- per-column BN stats over bf16 h (atomic combine) ----------------
__global__ void col_stats(const bf16* __restrict__ in, float* __restrict__ sums) {
    int c = threadIdx.x;  // 128
    int r0 = blockIdx.x * 256;
    int r1 = r0 + 256; if (r1 > Nn) r1 = Nn;
    float s = 0.f, s2 = 0.f;
    for (int r = r0; r < r1; ++r) {
        float v = ldb(&in[(size_t)r * HD + c]);
        s += v; s2 += v * v;
    }
    atomicAdd(&sums[c], s);
    atomicAdd(&sums[HD + c], s2);
}

__global__ void bn_finalize(const float* __restrict__ sums, const bf16* __restrict__ g,
                            const bf16* __restrict__ be, float* __restrict__ ss) {
    int c = threadIdx.x;  // 128
    float mu = sums[c] * (1.f / Nn);
    float var = sums[HD + c] * (1.f / Nn) - mu * mu;
    float sc = tof(g[c]) * rsqrtf(var + EPSV);
    ss[c] = sc;
    ss[HD + c] = tof(be[c]) - mu * sc;
}

extern "C" void kernel_launch(void* const* d_in, const int* in_sizes, int n_in,
                              void* d_out, int out_size, void* d_ws, size_t ws_size,
                              hipStream_t stream) {
    (void)in_sizes; (void)n_in; (void)out_size; (void)ws_size;
    const void* x = d_in[0];
    const int* src = (const int*)d_in[1];
    const int* dst = (const int*)d_in[2];

    char* ws = (char*)d_ws;
    size_t off = 0;
    auto alloc = [&](size_t bytes) {
        void* p = ws + off;
        off += (bytes + 255) & ~(size_t)255;
        return p;
    };
    // rs (38.4 MB) aliases xb+rb (51.2 MB): both dead before L2 GEMM writes rs.
    bf16* xb = (bf16*)alloc((size_t)Nn * 128 * 2);    // 25.6 MB (stride-128 padded x)
    bf16* rb = (bf16*)alloc((size_t)Nn * HD * 2);     // 25.6 MB
    bf16* rs = xb;                                    // [Nn][HCP] alias
    bf16* fs = (bf16*)alloc((size_t)Nn * HCP * 2);    // 38.4 MB
    bf16* fd = (bf16*)alloc((size_t)Nn * HCP * 2);    // 38.4 MB
    bf16* hbA = (bf16*)alloc((size_t)Nn * HD * 2);    // 25.6 MB
    bf16* hbB = (bf16*)alloc((size_t)Nn * HD * 2);    // 25.6 MB
    int* ptr = (int*)alloc((Nn + 1) * 4);             // 400 KB
    bf16* wtb = (bf16*)alloc((size_t)WROWS * 128 * 2);// 328 KB
    float* bns = (float*)alloc(2 * HD * 4);
    float* bnss0 = (float*)alloc(2 * HD * 4);
    float* bnss1 = (float*)alloc(2 * HD * 4);
    bf16* pb = (bf16*)alloc(4096 * 2);
    int* flag = (int*)alloc(256);

    // ---- small-param conversion (biases/attn/bn): d_in idx -> pb arena ----
    static const int spIdx[NSP] = {4, 6, 7, 9, 11, 13, 14, 16, 18, 19, 21, 22, 23, 24, 25};
    static const int spSz[NSP]  = {HD, HD, HD, HD, HD, HD, HD, HC, HC, HC, HC, HD, HD, HD, HD};
    CvtTab tab;
    int tot = 0;
    for (int i = 0; i < NSP; ++i) { tab.src[i] = d_in[spIdx[i]]; tab.off[i] = tot; tot += spSz[i]; }
    tab.off[NSP] = tot;
    const bf16 *bsrc0 = pb + tab.off[0], *bdst0 = pb + tab.off[1], *attn0 = pb + tab.off[2],
               *bres0 = pb + tab.off[3], *bsrc1 = pb + tab.off[4], *bdst1 = pb + tab.off[5],
               *attn1 = pb + tab.off[6], *bsrc2 = pb + tab.off[7], *bdst2 = pb + tab.off[8],
               *attn2 = pb + tab.off[9], *bres2 = pb + tab.off[10],
               *g0 = pb + tab.off[11], *be0 = pb + tab.off[12],
               *g1 = pb + tab.off[13], *be1 = pb + tab.off[14];

    // ---- packed Wt: rows [0,384)=L0, [384,640)=L1, [640,1216)=L2 @MP=192, pad->1280 ----
    PrepTab pt;
    static const int wIdx[8] = {3, 5, 8, 10, 12, 15, 17, 20};
    static const int wK[8]   = {INF_, INF_, INF_, HD, HD, HD, HD, HD};
    static const int wM[8]   = {HD, HD, HD, HD, HD, HC, HC, HC};
    static const int wMP[8]  = {128, 128, 128, 128, 128, 192, 192, 192};
    static const int wR0[8]  = {0, 128, 256, 384, 512, 640, 832, 1024};
    for (int i = 0; i < 8; ++i) {
        pt.src[i] = d_in[wIdx[i]]; pt.row0[i] = wR0[i];
        pt.K[i] = wK[i]; pt.M[i] = wM[i]; pt.MP[i] = wMP[i];
    }

    detect_dtype<<<1, 64, 0, stream>>>((const unsigned*)x, flag);
    cvt_x<<<(Nn * 128 + 255) / 256, 256, 0, stream>>>(x, xb, flag);
    cvt_params<<<(tot + 255) / 256, 256, 0, stream>>>(tab, pb, tot, flag);
    prep_all<<<(WROWS * 128 + 255) / 256, 256, 0, stream>>>(pt, wtb, flag);
    build_ptr<<<(Nn + 256) / 256, 256, 0, stream>>>(dst, ptr);

    const int fusedGrid = (Nn + 3) / 4;
    const int statsGrid = (Nn + 255) / 256;
    const int rowBlk = (Nn + 63) / 64;  // 1563

    // ---------------- layer 0 (384 cols: y=2 x CS=3, A fetched 2x) ----------------
    gemm_big<128, 3, 3, false, false, HD><<<dim3(rowBlk, 2), 256, 0, stream>>>(
        xb, wtb, bsrc0, bdst0, bres0, fs, fd, rb, HD, nullptr);
    gat_fused_128<false><<<fusedGrid, 256, 0, stream>>>(fs, fd, src, ptr, attn0,
                                                        rb, nullptr, hbA);
    zero_u32<<<1, 256, 0, stream>>>((unsigned*)bns, 2 * HD);
    col_stats<<<statsGrid, 128, 0, stream>>>(hbA, bns);
    bn_finalize<<<1, HD, 0, stream>>>(bns, g0, be0, bnss0);

    // ---------------- layer 1 ----------------
    gemm_big<128, 2, 2, true, false, HD><<<dim3(rowBlk, 2), 256, 0, stream>>>(
        hbA, wtb + (size_t)384 * 128, bsrc1, bdst1, nullptr, fs, fd, nullptr, HD, bnss0);
    gat_fused_128<true><<<fusedGrid, 256, 0, stream>>>(fs, fd, src, ptr, attn1,
                                                       hbA, bnss0, hbB);
    zero_u32<<<1, 256, 0, stream>>>((unsigned*)bns, 2 * HD);
    col_stats<<<statsGrid, 128, 0, stream>>>(hbB, bns);
    bn_finalize<<<1, HD, 0, stream>>>(bns, g1, be1, bnss1);

    // ---------------- layer 2 (padded head-major 48 stride-192 outputs) ----------------
    gemm_big<192, 3, 3, true, true, HCP><<<dim3(rowBlk, 3), 256, 0, stream>>>(
        hbB, wtb + (size_t)640 * 128, bsrc2, bdst2, bres2, fs, fd, rs, HC, bnss1);
    gat_fused_188<<<fusedGrid, 256, 0, stream>>>(fs, fd, src, ptr, attn2, rs,
                                                 d_out, flag);
}